// Round 10
// baseline (303.459 us; speedup 1.0000x reference)
//
#include <hip/hip_runtime.h>
#include <math.h>

// TensorTrainGaussian likelihood as a matvec chain:
//   u0 = softmax(wk0_logits); u_{m+1} = R_m(x_n) u_m;  out = log(sum(u_16) + EPS)
//   R_m[i,j] = exp2( A*x^2 + B*x + C ),  per-(m,i,j):
// A = -0.5/s^2*log2e, B = mu/s^2*log2e,
// C = (logW - log s - 0.5*log(2pi) - 0.5*mu^2/s^2)*log2e, s = softplus(pre_sigma)
// R10: deconfound R6 vs R8 -- scalar minimal stream (no asm) in the
// high-occupancy config (1024 thr, short-epilogue staging, VGPR-lean),
// with split accumulators to shorten the exp->fmac dep chain.

#define TTG_N 32768
#define TTG_M 16
#define TTG_K 64

typedef float f32x4 __attribute__((ext_vector_type(4)));

static constexpr float kHalfLog2Pi = 0.9189385332046727f;
static constexpr float kEps        = 2.220446049250313e-16f;
static constexpr float kLog2e      = 1.4426950408889634f;

#if defined(__has_builtin)
#if __has_builtin(__builtin_amdgcn_exp2f)
#define TTG_EXP2(x) __builtin_amdgcn_exp2f(x)
#else
#define TTG_EXP2(x) exp2f(x)
#endif
#else
#define TTG_EXP2(x) exp2f(x)
#endif

// ---------------- prep: wk0 = softmax(wk0_logits) ----------------
__global__ void ttg_prep_wk0(const float* __restrict__ logits,
                             float* __restrict__ wk0) {
  int i = threadIdx.x;  // 64 threads = 1 wave
  float l = logits[i];
  float mx = l;
  for (int d = 1; d < 64; d <<= 1) mx = fmaxf(mx, __shfl_xor(mx, d));
  float e = expf(l - mx);
  float s = e;
  for (int d = 1; d < 64; d <<= 1) s += __shfl_xor(s, d);
  wk0[i] = e / s;
}

// ---------------- prep: Horner coefficients, j-quad packed ----------------
// One wave per (m, j); lane = i. log_softmax over i (axis=1 of (M,K,K)).
// Per m (12288 floats): A4 [j/4][i][4] @0, B4 @4096, C4 @8192.
__global__ void ttg_prep_params(const float* __restrict__ W,
                                const float* __restrict__ mu,
                                const float* __restrict__ ps,
                                float* __restrict__ P) {
  int b = blockIdx.x;
  int m = b >> 6;
  int j = b & 63;
  int i = threadIdx.x;
  int idx = (m * TTG_K + i) * TTG_K + j;  // [m][i][j]

  float w = W[idx];
  float mx = w;
  for (int d = 1; d < 64; d <<= 1) mx = fmaxf(mx, __shfl_xor(mx, d));
  float e = expf(w - mx);
  float s = e;
  for (int d = 1; d < 64; d <<= 1) s += __shfl_xor(s, d);
  float lw = w - mx - logf(s);  // log_softmax over i

  float mv  = mu[idx];
  float sig = log1pf(expf(ps[idx]));  // jax.nn.softplus
  float inv2 = 1.0f / (sig * sig);
  float A = -0.5f * inv2 * kLog2e;
  float B = mv * inv2 * kLog2e;
  float C = (lw - logf(sig) - kHalfLog2Pi - 0.5f * mv * mv * inv2) * kLog2e;

  float* base = P + (size_t)m * 12288;
  int pi = ((j >> 2) * TTG_K + i) * 4 + (j & 3);
  base[pi]        = A;
  base[4096 + pi] = B;
  base[8192 + pi] = C;
}

// ---------------- main chain kernel ----------------
// 1024 threads (16 waves), 64 samples/block; wave w owns samples w*4..w*4+3.
// lane = i. 68 KB LDS -> 2 blocks/CU = 8 waves/SIMD (the R6 occupancy that
// keeps v_exp latency covered). Short-epilogue param staging (VGPR-lean;
// R4 spill lesson, R8 prefetch-occupancy lesson). j4 loop fully unrolled:
// every ds_read address is base + imm offset.
__global__ __launch_bounds__(1024, 4) void ttg_main(
    const float* __restrict__ X, const float* __restrict__ P,
    const float* __restrict__ wk0, float* __restrict__ out) {
  __shared__ __align__(16) float prA[TTG_K * TTG_K];  // 16 KB [j/4][i][4]
  __shared__ __align__(16) float prB[TTG_K * TTG_K];  // 16 KB
  __shared__ __align__(16) float prC[TTG_K * TTG_K];  // 16 KB
  __shared__ __align__(16) float ub[64 * TTG_K];      // 16 KB [sample][j]
  __shared__ __align__(16) float xbT[TTG_M * 64];     //  4 KB [m][sample]

  const int tid  = threadIdx.x;
  const int lane = tid & 63;
  const int wv   = __builtin_amdgcn_readfirstlane(tid >> 6);  // 0..15
  const int blk  = blockIdx.x;

  // stage X transposed: xbT[m][s] = X[blk*64+s][m]
  if (tid < 256) {
    float4 v = ((const float4*)X)[blk * 256 + tid];
    int s = tid >> 2, f0 = (tid & 3) * 4;
    xbT[(f0 + 0) * 64 + s] = v.x;
    xbT[(f0 + 1) * 64 + s] = v.y;
    xbT[(f0 + 2) * 64 + s] = v.z;
    xbT[(f0 + 3) * 64 + s] = v.w;
  }
  // u0[s][j] = wk0[j]
#pragma unroll
  for (int r = 0; r < 4; ++r) {
    int idx = tid + r * 1024;
    ub[idx] = wk0[idx & 63];
  }
  // stage m=0 params (3072 float4 / 1024 threads)
  {
    const float4* src = (const float4*)P;
    ((float4*)prA)[tid] = src[tid];
    ((float4*)prB)[tid] = src[1024 + tid];
    ((float4*)prC)[tid] = src[2048 + tid];
  }
  __syncthreads();

  float aE0, aO0, aE1, aO1, aE2, aO2, aE3, aO3;  // even/odd split accumulators
  for (int m = 0; m < TTG_M; ++m) {
    // wave-uniform x and x^2 for this wave's 4 samples (loop-invariant)
    const float* xr = xbT + m * 64 + wv * 4;
    const float x0 = xr[0], x1 = xr[1], x2 = xr[2], x3 = xr[3];
    const float y0 = x0 * x0, y1 = x1 * x1, y2 = x2 * x2, y3 = x3 * x3;

    aE0 = aO0 = aE1 = aO1 = aE2 = aO2 = aE3 = aO3 = 0.f;
    const f32x4* pA = ((const f32x4*)prA) + lane;
    const f32x4* pB = ((const f32x4*)prB) + lane;
    const f32x4* pC = ((const f32x4*)prC) + lane;
    const f32x4* pU = (const f32x4*)(ub + wv * 4 * TTG_K);  // 4 rows x 16 quads

// One sample-quad: 8 FMA + 4 exp + 4 fmac, two independent acc chains.
#define TTG_S(S, XS, YS, AE, AO)                                              \
    {                                                                         \
      const f32x4 u4 = pU[(S) * 16 + j4];                                     \
      float t0 = fmaf(a4[0], YS, fmaf(b4[0], XS, c4[0]));                     \
      float t1 = fmaf(a4[1], YS, fmaf(b4[1], XS, c4[1]));                     \
      float t2 = fmaf(a4[2], YS, fmaf(b4[2], XS, c4[2]));                     \
      float t3 = fmaf(a4[3], YS, fmaf(b4[3], XS, c4[3]));                     \
      AE = fmaf(TTG_EXP2(t0), u4[0], AE);                                     \
      AO = fmaf(TTG_EXP2(t1), u4[1], AO);                                     \
      AE = fmaf(TTG_EXP2(t2), u4[2], AE);                                     \
      AO = fmaf(TTG_EXP2(t3), u4[3], AO);                                     \
    }

#pragma unroll
    for (int j4 = 0; j4 < 16; ++j4) {
      const f32x4 a4 = pA[j4 * 64];  // ds_read_b128, imm offset
      const f32x4 b4 = pB[j4 * 64];
      const f32x4 c4 = pC[j4 * 64];
      TTG_S(0, x0, y0, aE0, aO0)
      TTG_S(1, x1, y1, aE1, aO1)
      TTG_S(2, x2, y2, aE2, aO2)
      TTG_S(3, x3, y3, aE3, aO3)
    }
#undef TTG_S

    if (m < TTG_M - 1) {
      __syncthreads();  // all waves done reading ub/params
      // u_{m+1}[s][i]: lane i writes its entry for the wave's 4 samples
      float* ud = ub + wv * 4 * TTG_K + lane;
      ud[0 * TTG_K] = aE0 + aO0;
      ud[1 * TTG_K] = aE1 + aO1;
      ud[2 * TTG_K] = aE2 + aO2;
      ud[3 * TTG_K] = aE3 + aO3;
      // stage next step's params: SHORT live range (load -> store)
      const float4* src = (const float4*)(P + (size_t)(m + 1) * 12288);
      float4 pf0 = src[tid];
      float4 pf1 = src[tid + 1024];
      float4 pf2 = src[tid + 2048];
      ((float4*)prA)[tid] = pf0;
      ((float4*)prB)[tid] = pf1;
      ((float4*)prC)[tid] = pf2;
      __syncthreads();
    }
  }

  // likelihood_s = sum_i -> wave shuffle reduce, then log
  float r[4] = {aE0 + aO0, aE1 + aO1, aE2 + aO2, aE3 + aO3};
#pragma unroll
  for (int c = 0; c < 4; ++c) {
#pragma unroll
    for (int d = 1; d < 64; d <<= 1) r[c] += __shfl_xor(r[c], d);
  }
  if (lane == 0) {
    const int s0 = blk * 64 + wv * 4;
#pragma unroll
    for (int c = 0; c < 4; ++c) out[s0 + c] = logf(r[c] + kEps);
  }
}

extern "C" void kernel_launch(void* const* d_in, const int* in_sizes, int n_in,
                              void* d_out, int out_size, void* d_ws, size_t ws_size,
                              hipStream_t stream) {
  const float* X   = (const float*)d_in[0];  // (N, M)
  const float* wl  = (const float*)d_in[1];  // (1, K)
  const float* W   = (const float*)d_in[2];  // (M, K, K)
  const float* mu  = (const float*)d_in[3];  // (M, K, K)
  const float* ps  = (const float*)d_in[4];  // (M, K, K)
  float* out = (float*)d_out;

  float* wk0 = (float*)d_ws;
  float* P   = wk0 + 256;

  ttg_prep_wk0<<<1, 64, 0, stream>>>(wl, wk0);
  ttg_prep_params<<<TTG_M * TTG_K, 64, 0, stream>>>(W, mu, ps, P);
  ttg_main<<<TTG_N / 64, 1024, 0, stream>>>(X, P, wk0, out);
}

// Round 11
// 267.220 us; speedup vs baseline: 1.1356x; 1.1356x over previous
//
#include <hip/hip_runtime.h>
#include <math.h>

// TensorTrainGaussian likelihood as a matvec chain:
//   u0 = softmax(wk0_logits); u_{m+1} = R_m(x_n) u_m;  out = log(sum(u_16) + EPS)
//   R_m[i,j] = exp2( (A*x + B)*x + C ),  per-(m,i,j):
// A = -0.5/s^2*log2e, B = mu/s^2*log2e,
// C = (logW - log s - 0.5*log(2pi) - 0.5*mu^2/s^2)*log2e, s = softplus(pre_sigma)
// R11 = R5's inner loop (the best-fitting, mov-free stream: elementwise-fma
// Horner, scalar v_exp, packed accumulate) + short-epilogue param staging
// (R6/R10 lesson: cross-loop prefetch regs cost occupancy; epilogue doesn't).

#define TTG_N 32768
#define TTG_M 16
#define TTG_K 64

typedef float f32x2 __attribute__((ext_vector_type(2)));

static constexpr float kHalfLog2Pi = 0.9189385332046727f;
static constexpr float kEps        = 2.220446049250313e-16f;
static constexpr float kLog2e      = 1.4426950408889634f;

#if defined(__has_builtin)
#if __has_builtin(__builtin_amdgcn_exp2f)
#define TTG_EXP2(x) __builtin_amdgcn_exp2f(x)
#else
#define TTG_EXP2(x) exp2f(x)
#endif
#else
#define TTG_EXP2(x) exp2f(x)
#endif

// ---------------- prep: wk0 = softmax(wk0_logits) ----------------
__global__ void ttg_prep_wk0(const float* __restrict__ logits,
                             float* __restrict__ wk0) {
  int i = threadIdx.x;  // 64 threads = 1 wave
  float l = logits[i];
  float mx = l;
  for (int d = 1; d < 64; d <<= 1) mx = fmaxf(mx, __shfl_xor(mx, d));
  float e = expf(l - mx);
  float s = e;
  for (int d = 1; d < 64; d <<= 1) s += __shfl_xor(s, d);
  wk0[i] = e / s;
}

// ---------------- prep: Horner coefficients, j-pair packed ----------------
// One wave per (m, j); lane = i. log_softmax over i (axis=1 of (M,K,K)).
// Per m (12288 floats): A2 [j/2][i][2] @0, B2 @4096, C2 @8192.
__global__ void ttg_prep_params(const float* __restrict__ W,
                                const float* __restrict__ mu,
                                const float* __restrict__ ps,
                                float* __restrict__ P) {
  int b = blockIdx.x;
  int m = b >> 6;
  int j = b & 63;
  int i = threadIdx.x;
  int idx = (m * TTG_K + i) * TTG_K + j;  // [m][i][j]

  float w = W[idx];
  float mx = w;
  for (int d = 1; d < 64; d <<= 1) mx = fmaxf(mx, __shfl_xor(mx, d));
  float e = expf(w - mx);
  float s = e;
  for (int d = 1; d < 64; d <<= 1) s += __shfl_xor(s, d);
  float lw = w - mx - logf(s);  // log_softmax over i

  float mv  = mu[idx];
  float sig = log1pf(expf(ps[idx]));  // jax.nn.softplus
  float inv2 = 1.0f / (sig * sig);
  float A = -0.5f * inv2 * kLog2e;
  float B = mv * inv2 * kLog2e;
  float C = (lw - logf(sig) - kHalfLog2Pi - 0.5f * mv * mv * inv2) * kLog2e;

  float* base = P + (size_t)m * 12288;
  int pi = ((j >> 1) * TTG_K + i) * 2 + (j & 1);
  base[pi]        = A;
  base[4096 + pi] = B;
  base[8192 + pi] = C;
}

// ---------------- main chain kernel ----------------
// 1024 threads (16 waves), 64 samples/block; wave w owns samples w*4..w*4+3.
// lane = i. 68 KB LDS -> 2 blocks/CU = 8 waves/SIMD. Params staged per step
// in a SHORT epilogue (VGPR-lean). j2 loop fully unrolled: every ds_read
// address is base + imm offset.
__global__ __launch_bounds__(1024, 4) void ttg_main(
    const float* __restrict__ X, const float* __restrict__ P,
    const float* __restrict__ wk0, float* __restrict__ out) {
  __shared__ __align__(16) float prA[TTG_K * TTG_K];  // 16 KB [j/2][i][2]
  __shared__ __align__(16) float prB[TTG_K * TTG_K];  // 16 KB
  __shared__ __align__(16) float prC[TTG_K * TTG_K];  // 16 KB
  __shared__ __align__(16) float ub[64 * TTG_K];      // 16 KB [sample][j]
  __shared__ __align__(16) float xbT[TTG_M * 64];     //  4 KB [m][sample]

  const int tid  = threadIdx.x;
  const int lane = tid & 63;
  const int wv   = __builtin_amdgcn_readfirstlane(tid >> 6);  // 0..15
  const int blk  = blockIdx.x;

  // stage X transposed: xbT[m][s] = X[blk*64+s][m]
  if (tid < 256) {
    float4 v = ((const float4*)X)[blk * 256 + tid];
    int s = tid >> 2, f0 = (tid & 3) * 4;
    xbT[(f0 + 0) * 64 + s] = v.x;
    xbT[(f0 + 1) * 64 + s] = v.y;
    xbT[(f0 + 2) * 64 + s] = v.z;
    xbT[(f0 + 3) * 64 + s] = v.w;
  }
  // u0[s][j] = wk0[j]
#pragma unroll
  for (int r = 0; r < 4; ++r) {
    int idx = tid + r * 1024;
    ub[idx] = wk0[idx & 63];
  }
  // stage m=0 params (3072 float4 / 1024 threads)
  {
    const float4* src = (const float4*)P;
    ((float4*)prA)[tid] = src[tid];
    ((float4*)prB)[tid] = src[1024 + tid];
    ((float4*)prC)[tid] = src[2048 + tid];
  }
  __syncthreads();

  f32x2 acc0, acc1, acc2, acc3;
  for (int m = 0; m < TTG_M; ++m) {
    // wave-uniform x splat pairs for this wave's 4 samples (loop-invariant)
    const float* xr = xbT + m * 64 + wv * 4;
    const f32x2 xs0 = {xr[0], xr[0]};
    const f32x2 xs1 = {xr[1], xr[1]};
    const f32x2 xs2 = {xr[2], xr[2]};
    const f32x2 xs3 = {xr[3], xr[3]};

    acc0 = acc1 = acc2 = acc3 = (f32x2){0.f, 0.f};
    const f32x2* pA = ((const f32x2*)prA) + lane;
    const f32x2* pB = ((const f32x2*)prB) + lane;
    const f32x2* pC = ((const f32x2*)prC) + lane;
    const f32x2* pU = (const f32x2*)(ub + wv * 4 * TTG_K);  // 4 rows x 32 pairs

#define TTG_SAMPLE(XS, UROW, ACC)                                             \
    {                                                                         \
      const f32x2 u2 = pU[(UROW) * 32 + j2];                                  \
      f32x2 h = __builtin_elementwise_fma(a2, XS, b2);                        \
      f32x2 t = __builtin_elementwise_fma(h, XS, c2);                         \
      f32x2 e2 = {TTG_EXP2(t[0]), TTG_EXP2(t[1])};                            \
      ACC = __builtin_elementwise_fma(e2, u2, ACC);                           \
    }

#pragma unroll
    for (int j2 = 0; j2 < 32; ++j2) {
      const f32x2 a2 = pA[j2 * 64];  // ds_read_b64, imm offset, 2-way (free)
      const f32x2 b2 = pB[j2 * 64];
      const f32x2 c2 = pC[j2 * 64];
      TTG_SAMPLE(xs0, 0, acc0)
      TTG_SAMPLE(xs1, 1, acc1)
      TTG_SAMPLE(xs2, 2, acc2)
      TTG_SAMPLE(xs3, 3, acc3)
    }
#undef TTG_SAMPLE

    if (m < TTG_M - 1) {
      __syncthreads();  // all waves done reading ub/params
      // u_{m+1}[s][i]: lane i writes its entry for the wave's 4 samples
      float* ud = ub + wv * 4 * TTG_K + lane;
      ud[0 * TTG_K] = acc0[0] + acc0[1];
      ud[1 * TTG_K] = acc1[0] + acc1[1];
      ud[2 * TTG_K] = acc2[0] + acc2[1];
      ud[3 * TTG_K] = acc3[0] + acc3[1];
      // stage next step's params: SHORT live range (load -> store)
      const float4* src = (const float4*)(P + (size_t)(m + 1) * 12288);
      float4 pf0 = src[tid];
      float4 pf1 = src[tid + 1024];
      float4 pf2 = src[tid + 2048];
      ((float4*)prA)[tid] = pf0;
      ((float4*)prB)[tid] = pf1;
      ((float4*)prC)[tid] = pf2;
      __syncthreads();
    }
  }

  // likelihood_s = sum_i -> wave shuffle reduce, then log
  float r[4] = {acc0[0] + acc0[1], acc1[0] + acc1[1],
                acc2[0] + acc2[1], acc3[0] + acc3[1]};
#pragma unroll
  for (int c = 0; c < 4; ++c) {
#pragma unroll
    for (int d = 1; d < 64; d <<= 1) r[c] += __shfl_xor(r[c], d);
  }
  if (lane == 0) {
    const int s0 = blk * 64 + wv * 4;
#pragma unroll
    for (int c = 0; c < 4; ++c) out[s0 + c] = logf(r[c] + kEps);
  }
}

extern "C" void kernel_launch(void* const* d_in, const int* in_sizes, int n_in,
                              void* d_out, int out_size, void* d_ws, size_t ws_size,
                              hipStream_t stream) {
  const float* X   = (const float*)d_in[0];  // (N, M)
  const float* wl  = (const float*)d_in[1];  // (1, K)
  const float* W   = (const float*)d_in[2];  // (M, K, K)
  const float* mu  = (const float*)d_in[3];  // (M, K, K)
  const float* ps  = (const float*)d_in[4];  // (M, K, K)
  float* out = (float*)d_out;

  float* wk0 = (float*)d_ws;
  float* P   = wk0 + 256;

  ttg_prep_wk0<<<1, 64, 0, stream>>>(wl, wk0);
  ttg_prep_params<<<TTG_M * TTG_K, 64, 0, stream>>>(W, mu, ps, P);
  ttg_main<<<TTG_N / 64, 1024, 0, stream>>>(X, P, wk0, out);
}

// Round 13
// 247.967 us; speedup vs baseline: 1.2238x; 1.0776x over previous
//
#include <hip/hip_runtime.h>
#include <math.h>

// TensorTrainGaussian likelihood as a matvec chain:
//   u0 = softmax(wk0_logits); u_{m+1} = R_m(x_n) u_m;  out = log(sum(u_16) + EPS)
//   R_m[i,j] = exp2( (A*x + B)*x + C ),  per-(m,i,j):
// A = -0.5/s^2*log2e, B = mu/s^2*log2e,
// C = (logW - log s - 0.5*log(2pi) - 0.5*mu^2/s^2)*log2e, s = softplus(pre_sigma)
// R13 = R12 with the LDS-contiguity bug fixed: the three coefficient planes
// live in ONE __shared__ array (explicit offsets) so the single staging loop
// that walks 3*1024 float4s is correct by construction. (Separate __shared__
// arrays have no guaranteed adjacency -- R12's NaN.)

#define TTG_N 32768
#define TTG_M 16
#define TTG_K 64

typedef float f32x2 __attribute__((ext_vector_type(2)));

static constexpr float kHalfLog2Pi = 0.9189385332046727f;
static constexpr float kEps        = 2.220446049250313e-16f;
static constexpr float kLog2e      = 1.4426950408889634f;

#if defined(__has_builtin)
#if __has_builtin(__builtin_amdgcn_exp2f)
#define TTG_EXP2(x) __builtin_amdgcn_exp2f(x)
#else
#define TTG_EXP2(x) exp2f(x)
#endif
#else
#define TTG_EXP2(x) exp2f(x)
#endif

// ---------------- prep: wk0 = softmax(wk0_logits) ----------------
__global__ void ttg_prep_wk0(const float* __restrict__ logits,
                             float* __restrict__ wk0) {
  int i = threadIdx.x;  // 64 threads = 1 wave
  float l = logits[i];
  float mx = l;
  for (int d = 1; d < 64; d <<= 1) mx = fmaxf(mx, __shfl_xor(mx, d));
  float e = expf(l - mx);
  float s = e;
  for (int d = 1; d < 64; d <<= 1) s += __shfl_xor(s, d);
  wk0[i] = e / s;
}

// ---------------- prep: Horner coefficients, j-pair packed ----------------
// One wave per (m, j); lane = i. log_softmax over i (axis=1 of (M,K,K)).
// Per m (12288 floats): A2 [j/2][i][2] @0, B2 @4096, C2 @8192.
__global__ void ttg_prep_params(const float* __restrict__ W,
                                const float* __restrict__ mu,
                                const float* __restrict__ ps,
                                float* __restrict__ P) {
  int b = blockIdx.x;
  int m = b >> 6;
  int j = b & 63;
  int i = threadIdx.x;
  int idx = (m * TTG_K + i) * TTG_K + j;  // [m][i][j]

  float w = W[idx];
  float mx = w;
  for (int d = 1; d < 64; d <<= 1) mx = fmaxf(mx, __shfl_xor(mx, d));
  float e = expf(w - mx);
  float s = e;
  for (int d = 1; d < 64; d <<= 1) s += __shfl_xor(s, d);
  float lw = w - mx - logf(s);  // log_softmax over i

  float mv  = mu[idx];
  float sig = log1pf(expf(ps[idx]));  // jax.nn.softplus
  float inv2 = 1.0f / (sig * sig);
  float A = -0.5f * inv2 * kLog2e;
  float B = mv * inv2 * kLog2e;
  float C = (lw - logf(sig) - kHalfLog2Pi - 0.5f * mv * mv * inv2) * kLog2e;

  float* base = P + (size_t)m * 12288;
  int pi = ((j >> 1) * TTG_K + i) * 2 + (j & 1);
  base[pi]        = A;
  base[4096 + pi] = B;
  base[8192 + pi] = C;
}

// ---------------- main chain kernel ----------------
// 1024 threads (16 waves), 64 samples/block; wave w owns samples w*4..w*4+3.
// lane = i. 68 KB LDS -> 2 blocks/CU; VGPR capped at 32 by (1024,8) so each
// SIMD carries 8 waves while keeping R11's mov-free inner stream. j2 loop
// fully unrolled: ds_read = base + imm offset.
__global__ __launch_bounds__(1024, 8) void ttg_main(
    const float* __restrict__ X, const float* __restrict__ P,
    const float* __restrict__ wk0, float* __restrict__ out) {
  __shared__ __align__(16) float pr[3 * TTG_K * TTG_K];  // 48 KB: A@0 B@4096 C@8192
  __shared__ __align__(16) float ub[64 * TTG_K];         // 16 KB [sample][j]
  __shared__ __align__(16) float xbT[TTG_M * 64];        //  4 KB [m][sample]

  const int tid  = threadIdx.x;
  const int lane = tid & 63;
  const int wv   = __builtin_amdgcn_readfirstlane(tid >> 6);  // 0..15
  const int blk  = blockIdx.x;

  // stage X transposed: xbT[m][s] = X[blk*64+s][m]
  if (tid < 256) {
    float4 v = ((const float4*)X)[blk * 256 + tid];
    int s = tid >> 2, f0 = (tid & 3) * 4;
    xbT[(f0 + 0) * 64 + s] = v.x;
    xbT[(f0 + 1) * 64 + s] = v.y;
    xbT[(f0 + 2) * 64 + s] = v.z;
    xbT[(f0 + 3) * 64 + s] = v.w;
  }
  // u0[s][j] = wk0[j]
#pragma unroll
  for (int r = 0; r < 4; ++r) {
    int idx = tid + r * 1024;
    ub[idx] = wk0[idx & 63];
  }
  // stage m=0 params (3072 float4 / 1024 threads), 4-reg footprint
  {
#pragma unroll 1
    for (int r = 0; r < 3; ++r) {
      float4 v = ((const float4*)P)[r * 1024 + tid];
      ((float4*)pr)[r * 1024 + tid] = v;
    }
  }
  __syncthreads();

  f32x2 acc0, acc1, acc2, acc3;
  for (int m = 0; m < TTG_M; ++m) {
    // wave-uniform x splat pairs for this wave's 4 samples (loop-invariant)
    const float* xr = xbT + m * 64 + wv * 4;
    const f32x2 xs0 = {xr[0], xr[0]};
    const f32x2 xs1 = {xr[1], xr[1]};
    const f32x2 xs2 = {xr[2], xr[2]};
    const f32x2 xs3 = {xr[3], xr[3]};

    acc0 = acc1 = acc2 = acc3 = (f32x2){0.f, 0.f};
    const f32x2* pA = ((const f32x2*)pr) + lane;           // plane A @ 0
    const f32x2* pB = ((const f32x2*)(pr + 4096)) + lane;  // plane B
    const f32x2* pC = ((const f32x2*)(pr + 8192)) + lane;  // plane C
    const f32x2* pU = (const f32x2*)(ub + wv * 4 * TTG_K);  // 4 rows x 32 pairs

#define TTG_SAMPLE(XS, UROW, ACC)                                             \
    {                                                                         \
      const f32x2 u2 = pU[(UROW) * 32 + j2];                                  \
      f32x2 h = __builtin_elementwise_fma(a2, XS, b2);                        \
      f32x2 t = __builtin_elementwise_fma(h, XS, c2);                         \
      f32x2 e2 = {TTG_EXP2(t[0]), TTG_EXP2(t[1])};                            \
      ACC = __builtin_elementwise_fma(e2, u2, ACC);                           \
    }

#pragma unroll
    for (int j2 = 0; j2 < 32; ++j2) {
      const f32x2 a2 = pA[j2 * 64];  // ds_read_b64, imm offset, 2-way (free)
      const f32x2 b2 = pB[j2 * 64];
      const f32x2 c2 = pC[j2 * 64];
      TTG_SAMPLE(xs0, 0, acc0)
      TTG_SAMPLE(xs1, 1, acc1)
      TTG_SAMPLE(xs2, 2, acc2)
      TTG_SAMPLE(xs3, 3, acc3)
    }
#undef TTG_SAMPLE

    if (m < TTG_M - 1) {
      __syncthreads();  // all waves done reading ub/params
      // u_{m+1}[s][i]: lane i writes its entry for the wave's 4 samples
      float* ud = ub + wv * 4 * TTG_K + lane;
      ud[0 * TTG_K] = acc0[0] + acc0[1];
      ud[1 * TTG_K] = acc1[0] + acc1[1];
      ud[2 * TTG_K] = acc2[0] + acc2[1];
      ud[3 * TTG_K] = acc3[0] + acc3[1];
      // stage next step's params: 4-reg footprint (nounroll load->store);
      // pr is one contiguous array so one index covers all three planes
      const float4* src = (const float4*)(P + (size_t)(m + 1) * 12288);
#pragma unroll 1
      for (int r = 0; r < 3; ++r) {
        float4 v = src[r * 1024 + tid];
        ((float4*)pr)[r * 1024 + tid] = v;
      }
      __syncthreads();
    }
  }

  // likelihood_s = sum_i -> wave shuffle reduce, then log
  float r[4] = {acc0[0] + acc0[1], acc1[0] + acc1[1],
                acc2[0] + acc2[1], acc3[0] + acc3[1]};
#pragma unroll
  for (int c = 0; c < 4; ++c) {
#pragma unroll
    for (int d = 1; d < 64; d <<= 1) r[c] += __shfl_xor(r[c], d);
  }
  if (lane == 0) {
    const int s0 = blk * 64 + wv * 4;
#pragma unroll
    for (int c = 0; c < 4; ++c) out[s0 + c] = logf(r[c] + kEps);
  }
}

extern "C" void kernel_launch(void* const* d_in, const int* in_sizes, int n_in,
                              void* d_out, int out_size, void* d_ws, size_t ws_size,
                              hipStream_t stream) {
  const float* X   = (const float*)d_in[0];  // (N, M)
  const float* wl  = (const float*)d_in[1];  // (1, K)
  const float* W   = (const float*)d_in[2];  // (M, K, K)
  const float* mu  = (const float*)d_in[3];  // (M, K, K)
  const float* ps  = (const float*)d_in[4];  // (M, K, K)
  float* out = (float*)d_out;

  float* wk0 = (float*)d_ws;
  float* P   = wk0 + 256;

  ttg_prep_wk0<<<1, 64, 0, stream>>>(wl, wk0);
  ttg_prep_params<<<TTG_M * TTG_K, 64, 0, stream>>>(W, mu, ps, P);
  ttg_main<<<TTG_N / 64, 1024, 0, stream>>>(X, P, wk0, out);
}

// Round 14
// 244.634 us; speedup vs baseline: 1.2405x; 1.0136x over previous
//
#include <hip/hip_runtime.h>
#include <math.h>

// TensorTrainGaussian likelihood as a matvec chain:
//   u0 = softmax(wk0_logits); u_{m+1} = R_m(x_n) u_m;  out = log(sum(u_16) + EPS)
//   R_m[i,j] = exp2( (A*x + B)*x + C ),  per-(m,i,j):
// A = -0.5/s^2*log2e, B = mu/s^2*log2e,
// C = (logW - log s - 0.5*log(2pi) - 0.5*mu^2/s^2)*log2e, s = softplus(pre_sigma)
// R14 = R13 + (1) async param staging via global_load_lds width=16 (zero
// staging VGPRs, no load->store round trip; drains at the barrier's vmcnt(0))
// + (2) j4 b128 LDS reads (params [j/4][i][4]) halving ds issue count.

#define TTG_N 32768
#define TTG_M 16
#define TTG_K 64

typedef float f32x2 __attribute__((ext_vector_type(2)));
typedef float f32x4 __attribute__((ext_vector_type(4)));

static constexpr float kHalfLog2Pi = 0.9189385332046727f;
static constexpr float kEps        = 2.220446049250313e-16f;
static constexpr float kLog2e      = 1.4426950408889634f;

#if defined(__has_builtin)
#if __has_builtin(__builtin_amdgcn_exp2f)
#define TTG_EXP2(x) __builtin_amdgcn_exp2f(x)
#else
#define TTG_EXP2(x) exp2f(x)
#endif
#else
#define TTG_EXP2(x) exp2f(x)
#endif

// async global->LDS copy, 16 B per lane; LDS dest = wave-uniform base + lane*16
#define TTG_GLOAD_LDS(gp, lp)                                                 \
  __builtin_amdgcn_global_load_lds(                                           \
      (const __attribute__((address_space(1))) void*)(gp),                    \
      (__attribute__((address_space(3))) void*)(lp), 16, 0, 0)

// ---------------- prep: wk0 = softmax(wk0_logits) ----------------
__global__ void ttg_prep_wk0(const float* __restrict__ logits,
                             float* __restrict__ wk0) {
  int i = threadIdx.x;  // 64 threads = 1 wave
  float l = logits[i];
  float mx = l;
  for (int d = 1; d < 64; d <<= 1) mx = fmaxf(mx, __shfl_xor(mx, d));
  float e = expf(l - mx);
  float s = e;
  for (int d = 1; d < 64; d <<= 1) s += __shfl_xor(s, d);
  wk0[i] = e / s;
}

// ---------------- prep: Horner coefficients, j-quad packed ----------------
// One wave per (m, j); lane = i. log_softmax over i (axis=1 of (M,K,K)).
// Per m (12288 floats): A4 [j/4][i][4] @0, B4 @4096, C4 @8192.
__global__ void ttg_prep_params(const float* __restrict__ W,
                                const float* __restrict__ mu,
                                const float* __restrict__ ps,
                                float* __restrict__ P) {
  int b = blockIdx.x;
  int m = b >> 6;
  int j = b & 63;
  int i = threadIdx.x;
  int idx = (m * TTG_K + i) * TTG_K + j;  // [m][i][j]

  float w = W[idx];
  float mx = w;
  for (int d = 1; d < 64; d <<= 1) mx = fmaxf(mx, __shfl_xor(mx, d));
  float e = expf(w - mx);
  float s = e;
  for (int d = 1; d < 64; d <<= 1) s += __shfl_xor(s, d);
  float lw = w - mx - logf(s);  // log_softmax over i

  float mv  = mu[idx];
  float sig = log1pf(expf(ps[idx]));  // jax.nn.softplus
  float inv2 = 1.0f / (sig * sig);
  float A = -0.5f * inv2 * kLog2e;
  float B = mv * inv2 * kLog2e;
  float C = (lw - logf(sig) - kHalfLog2Pi - 0.5f * mv * mv * inv2) * kLog2e;

  float* base = P + (size_t)m * 12288;
  int pi = ((j >> 2) * TTG_K + i) * 4 + (j & 3);
  base[pi]        = A;
  base[4096 + pi] = B;
  base[8192 + pi] = C;
}

// ---------------- main chain kernel ----------------
// 1024 threads (16 waves), 64 samples/block; wave w owns samples w*4..w*4+3.
// lane = i. 68 KB LDS -> 2 blocks/CU; VGPR capped at 32 by (1024,8) -> 8
// waves/SIMD. Param staging is 3 async global_load_lds per thread-slot (no
// VGPRs, drains at the barrier). j4 loop fully unrolled: ds = base + imm.
__global__ __launch_bounds__(1024, 8) void ttg_main(
    const float* __restrict__ X, const float* __restrict__ P,
    const float* __restrict__ wk0, float* __restrict__ out) {
  __shared__ __align__(16) float pr[3 * TTG_K * TTG_K];  // 48 KB: A@0 B@4096 C@8192
  __shared__ __align__(16) float ub[64 * TTG_K];         // 16 KB [sample][j]
  __shared__ __align__(16) float xbT[TTG_M * 64];        //  4 KB [m][sample]

  const int tid  = threadIdx.x;
  const int lane = tid & 63;
  const int wv   = __builtin_amdgcn_readfirstlane(tid >> 6);  // 0..15
  const int blk  = blockIdx.x;

  // kick off m=0 param staging: LDS dest base is wave-uniform (wv), global
  // src is per-lane; 16 B/lane x 64 lanes x 16 waves x 3 = 48 KB
  {
    const float* src = P + (size_t)(wv * 64 + lane) * 4;
    float* dst = pr + wv * 256;  // wave-uniform (lane*16 B added by HW)
    TTG_GLOAD_LDS(src, dst);
    TTG_GLOAD_LDS(src + 4096, dst + 4096);
    TTG_GLOAD_LDS(src + 8192, dst + 8192);
  }
  // stage X transposed: xbT[m][s] = X[blk*64+s][m]
  if (tid < 256) {
    float4 v = ((const float4*)X)[blk * 256 + tid];
    int s = tid >> 2, f0 = (tid & 3) * 4;
    xbT[(f0 + 0) * 64 + s] = v.x;
    xbT[(f0 + 1) * 64 + s] = v.y;
    xbT[(f0 + 2) * 64 + s] = v.z;
    xbT[(f0 + 3) * 64 + s] = v.w;
  }
  // u0[s][j] = wk0[j]
#pragma unroll
  for (int r = 0; r < 4; ++r) {
    int idx = tid + r * 1024;
    ub[idx] = wk0[idx & 63];
  }
  __syncthreads();  // drains vmcnt -> m=0 params resident

  f32x2 acc0, acc1, acc2, acc3;
  for (int m = 0; m < TTG_M; ++m) {
    // wave-uniform x splat pairs for this wave's 4 samples (loop-invariant)
    const float* xr = xbT + m * 64 + wv * 4;
    const f32x2 xs0 = {xr[0], xr[0]};
    const f32x2 xs1 = {xr[1], xr[1]};
    const f32x2 xs2 = {xr[2], xr[2]};
    const f32x2 xs3 = {xr[3], xr[3]};

    acc0 = acc1 = acc2 = acc3 = (f32x2){0.f, 0.f};
    const f32x4* pA = ((const f32x4*)pr) + lane;           // plane A @ 0
    const f32x4* pB = ((const f32x4*)(pr + 4096)) + lane;  // plane B
    const f32x4* pC = ((const f32x4*)(pr + 8192)) + lane;  // plane C
    const f32x4* pU = (const f32x4*)(ub + wv * 4 * TTG_K);  // 4 rows x 16 quads

// One sample: u-quad b128 broadcast; Horner + acc on the quad's two halves.
#define TTG_S(S, XS, ACC)                                                     \
    {                                                                         \
      const f32x4 u4 = pU[(S) * 16 + j4];                                     \
      const f32x2 ulo = __builtin_shufflevector(u4, u4, 0, 1);                \
      const f32x2 uhi = __builtin_shufflevector(u4, u4, 2, 3);                \
      f32x2 h0 = __builtin_elementwise_fma(alo, XS, blo);                     \
      f32x2 t0 = __builtin_elementwise_fma(h0, XS, clo);                      \
      f32x2 h1 = __builtin_elementwise_fma(ahi, XS, bhi);                     \
      f32x2 t1 = __builtin_elementwise_fma(h1, XS, chi);                      \
      f32x2 e0 = {TTG_EXP2(t0[0]), TTG_EXP2(t0[1])};                          \
      f32x2 e1 = {TTG_EXP2(t1[0]), TTG_EXP2(t1[1])};                          \
      ACC = __builtin_elementwise_fma(e0, ulo, ACC);                          \
      ACC = __builtin_elementwise_fma(e1, uhi, ACC);                          \
    }

#pragma unroll
    for (int j4 = 0; j4 < 16; ++j4) {
      const f32x4 a4 = pA[j4 * 64];  // ds_read_b128, imm offset
      const f32x4 b4 = pB[j4 * 64];
      const f32x4 c4 = pC[j4 * 64];
      const f32x2 alo = __builtin_shufflevector(a4, a4, 0, 1);
      const f32x2 ahi = __builtin_shufflevector(a4, a4, 2, 3);
      const f32x2 blo = __builtin_shufflevector(b4, b4, 0, 1);
      const f32x2 bhi = __builtin_shufflevector(b4, b4, 2, 3);
      const f32x2 clo = __builtin_shufflevector(c4, c4, 0, 1);
      const f32x2 chi = __builtin_shufflevector(c4, c4, 2, 3);
      TTG_S(0, xs0, acc0)
      TTG_S(1, xs1, acc1)
      TTG_S(2, xs2, acc2)
      TTG_S(3, xs3, acc3)
    }
#undef TTG_S

    if (m < TTG_M - 1) {
      __syncthreads();  // all waves done reading ub/params
      // u_{m+1}[s][i]: lane i writes its entry for the wave's 4 samples
      float* ud = ub + wv * 4 * TTG_K + lane;
      ud[0 * TTG_K] = acc0[0] + acc0[1];
      ud[1 * TTG_K] = acc1[0] + acc1[1];
      ud[2 * TTG_K] = acc2[0] + acc2[1];
      ud[3 * TTG_K] = acc3[0] + acc3[1];
      // stage next step's params: async DMA, no VGPRs, drains at the barrier
      const float* src = P + (size_t)(m + 1) * 12288 + (size_t)(wv * 64 + lane) * 4;
      float* dst = pr + wv * 256;  // wave-uniform base
      TTG_GLOAD_LDS(src, dst);
      TTG_GLOAD_LDS(src + 4096, dst + 4096);
      TTG_GLOAD_LDS(src + 8192, dst + 8192);
      __syncthreads();
    }
  }

  // likelihood_s = sum_i -> wave shuffle reduce, then log
  float r[4] = {acc0[0] + acc0[1], acc1[0] + acc1[1],
                acc2[0] + acc2[1], acc3[0] + acc3[1]};
#pragma unroll
  for (int c = 0; c < 4; ++c) {
#pragma unroll
    for (int d = 1; d < 64; d <<= 1) r[c] += __shfl_xor(r[c], d);
  }
  if (lane == 0) {
    const int s0 = blk * 64 + wv * 4;
#pragma unroll
    for (int c = 0; c < 4; ++c) out[s0 + c] = logf(r[c] + kEps);
  }
}

extern "C" void kernel_launch(void* const* d_in, const int* in_sizes, int n_in,
                              void* d_out, int out_size, void* d_ws, size_t ws_size,
                              hipStream_t stream) {
  const float* X   = (const float*)d_in[0];  // (N, M)
  const float* wl  = (const float*)d_in[1];  // (1, K)
  const float* W   = (const float*)d_in[2];  // (M, K, K)
  const float* mu  = (const float*)d_in[3];  // (M, K, K)
  const float* ps  = (const float*)d_in[4];  // (M, K, K)
  float* out = (float*)d_out;

  float* wk0 = (float*)d_ws;
  float* P   = wk0 + 256;

  ttg_prep_wk0<<<1, 64, 0, stream>>>(wl, wk0);
  ttg_prep_params<<<TTG_M * TTG_K, 64, 0, stream>>>(W, mu, ps, P);
  ttg_main<<<TTG_N / 64, 1024, 0, stream>>>(X, P, wk0, out);
}